// Round 6
// baseline (396.437 us; speedup 1.0000x reference)
//
#include <hip/hip_runtime.h>

#define T_SEQ 2048

typedef __bf16 bf16x8 __attribute__((ext_vector_type(8)));
typedef float f32x4 __attribute__((ext_vector_type(4)));
typedef unsigned short u16;

__device__ __forceinline__ u16 f2b(float f) {
  unsigned u = __float_as_uint(f);
  unsigned r = 0x7fffu + ((u >> 16) & 1u);
  return (u16)((u + r) >> 16);
}
__device__ __forceinline__ float b2f(u16 v) {
  return __uint_as_float(((unsigned)v) << 16);
}
__device__ __forceinline__ f32x4 mfma16(bf16x8 a, bf16x8 b, f32x4 c) {
  return __builtin_amdgcn_mfma_f32_16x16x32_bf16(a, b, c, 0, 0, 0);
}
// pack two f32 -> two bf16 (RTZ) in ONE v_perm_b32 (truncation ~ bf16 noise).
__device__ __forceinline__ unsigned pkhi(float lo, float hi) {
  return __builtin_amdgcn_perm(__float_as_uint(hi), __float_as_uint(lo), 0x07060302u);
}
// raw exp2 (no OCML denormal fixup; -1e30 underflows to 0 which is what we want)
#if defined(__has_builtin)
#if __has_builtin(__builtin_amdgcn_exp2f)
#define HAVE_RAW_EXP2 1
#endif
#endif
__device__ __forceinline__ float exp2r(float x) {
#ifdef HAVE_RAW_EXP2
  return __builtin_amdgcn_exp2f(x);
#else
  float r;
  asm("v_exp_f32 %0, %1" : "=v"(r) : "v"(x));
  return r;
#endif
}
// async global->LDS, 16B per lane; LDS dest = wave-uniform base + lane*16
__device__ __forceinline__ void glds16(const void* g, void* s) {
  __builtin_amdgcn_global_load_lds(
      (const __attribute__((address_space(1))) void*)(uintptr_t)g,
      (__attribute__((address_space(3))) void*)(unsigned)(uintptr_t)s, 16, 0, 0);
}

// ---------------- lambda scalar ----------------
__global__ void lam_kernel(const float* __restrict__ q1, const float* __restrict__ k1,
                           const float* __restrict__ q2, const float* __restrict__ k2,
                           float* __restrict__ outp) {
  int l = threadIdx.x;
  float a = q1[l] * k1[l];
  float c = q2[l] * k2[l];
  #pragma unroll
  for (int off = 32; off > 0; off >>= 1) {
    a += __shfl_down(a, off);
    c += __shfl_down(c, off);
  }
  if (l == 0) outp[0] = expf(a) - expf(c) + 0.7836057665316244f;  // + LAMBDA_INIT
}

// ---------------- fp32 -> bf16 convert ----------------
__global__ __launch_bounds__(256) void convert_kernel(const float* __restrict__ in,
                                                      u16* __restrict__ outp, int n) {
  int i = (blockIdx.x * 256 + threadIdx.x) * 4;
  if (i >= n) return;
  float4 v = *(const float4*)(in + i);
  ushort4 pk;
  pk.x = f2b(v.x); pk.y = f2b(v.y); pk.z = f2b(v.z); pk.w = f2b(v.w);
  *(ushort4*)(outp + i) = pk;
}

// ---------------- transpose fp32[R][C] -> bf16[C][R] ----------------
__global__ __launch_bounds__(256) void transpose_kernel(const float* __restrict__ in,
                                                        u16* __restrict__ outp, int R, int C) {
  __shared__ float tile[32][33];
  int c0 = blockIdx.x * 32, r0 = blockIdx.y * 32;
  int tx = threadIdx.x & 31, ty = threadIdx.x >> 5;
  #pragma unroll
  for (int k2 = 0; k2 < 4; k2++)
    tile[ty * 4 + k2][tx] = in[(size_t)(r0 + ty * 4 + k2) * C + c0 + tx];
  __syncthreads();
  #pragma unroll
  for (int k2 = 0; k2 < 4; k2++)
    outp[(size_t)(c0 + ty * 4 + k2) * R + r0 + tx] = f2b(tile[tx][ty * 4 + k2]);
}

// ---------------- m97-style GEMM: C[M][N] = A[M][K] @ BT[N][K]^T ----------------
template <bool OUT_BF16>
__global__ __launch_bounds__(256) void gemm128_kernel(const u16* __restrict__ A,
                                                      const u16* __restrict__ BT,
                                                      void* __restrict__ C, int N, int K) {
  __shared__ alignas(16) u16 As[128 * 64];
  __shared__ alignas(16) u16 Bs[128 * 64];
  const int tid = threadIdx.x, w = tid >> 6, lane = tid & 63;
  const int l15 = lane & 15, quad = lane >> 4;
  const int m0 = blockIdx.y * 128, n0 = blockIdx.x * 128;
  const int wm = (w >> 1) * 64, wn = (w & 1) * 64;
  const int lr = lane >> 3, slot = lane & 7, csw = slot ^ lr;
  f32x4 acc[4][4];
  #pragma unroll
  for (int mt = 0; mt < 4; mt++)
    #pragma unroll
    for (int nt = 0; nt < 4; nt++) acc[mt][nt] = (f32x4){0.f, 0.f, 0.f, 0.f};
  const u16* Ag = A + (size_t)(m0 + w * 32 + lr) * K + csw * 8;
  const u16* Bg = BT + (size_t)(n0 + w * 32 + lr) * K + csw * 8;
  u16* Asd = As + (w * 32) * 64;
  u16* Bsd = Bs + (w * 32) * 64;
  for (int kt = 0; kt < K; kt += 64) {
    #pragma unroll
    for (int i = 0; i < 4; i++) {
      glds16(Ag + kt + (size_t)(i * 8) * K, Asd + i * 512);
      glds16(Bg + kt + (size_t)(i * 8) * K, Bsd + i * 512);
    }
    __syncthreads();
    #pragma unroll
    for (int kk = 0; kk < 2; kk++) {
      bf16x8 am[4], bn[4];
      #pragma unroll
      for (int t = 0; t < 4; t++) {
        const int ra = wm + t * 16 + l15;
        am[t] = *(const bf16x8*)&As[ra * 64 + (((kk * 4 + quad) ^ (ra & 7)) << 3)];
        const int rb = wn + t * 16 + l15;
        bn[t] = *(const bf16x8*)&Bs[rb * 64 + (((kk * 4 + quad) ^ (rb & 7)) << 3)];
      }
      #pragma unroll
      for (int mt = 0; mt < 4; mt++)
        #pragma unroll
        for (int nt = 0; nt < 4; nt++) acc[mt][nt] = mfma16(am[mt], bn[nt], acc[mt][nt]);
    }
    __syncthreads();
  }
  const int row = m0 + wm + quad * 4;
  #pragma unroll
  for (int mt = 0; mt < 4; mt++) {
    #pragma unroll
    for (int nt = 0; nt < 4; nt++) {
      const int col = n0 + wn + nt * 16 + l15;
      #pragma unroll
      for (int rr = 0; rr < 4; rr++) {
        if (OUT_BF16)
          ((u16*)C)[(size_t)(row + mt * 16 + rr) * N + col] = f2b(acc[mt][nt][rr]);
        else
          ((float*)C)[(size_t)(row + mt * 16 + rr) * N + col] = acc[mt][nt][rr];
      }
    }
  }
}

// ---------------- rotary + transpose: QKV[B*T][4096] -> out[B][nh][T][64] ----------------
__global__ __launch_bounds__(256) void rotary_kernel(const u16* __restrict__ qkv,
                                                     u16* __restrict__ outp, int lh,
                                                     int colbase, float scale) {
  int idx = blockIdx.x * 256 + threadIdx.x;
  int i = idx & 31;
  int h = (idx >> 5) & ((1 << lh) - 1);
  int bt = idx >> (5 + lh);
  int t = bt & (T_SEQ - 1);
  size_t inb = (size_t)bt * 4096 + colbase + h * 64 + i;
  float x1 = b2f(qkv[inb]);
  float x2 = b2f(qkv[inb + 32]);
  float invf = exp2f(-(float)i * 0.4152410118609203f);
  float ang = (float)t * invf;
  float c = cosf(ang), s = sinf(ang);
  float o1 = (x1 * c + x2 * s) * scale;
  float o2 = (x2 * c - x1 * s) * scale;
  size_t ob = ((size_t)((bt >> 11) * (1 << lh) + h) * T_SEQ + t) * 64 + i;
  outp[ob] = f2b(o1);
  outp[ob + 32] = f2b(o2);
}

// ---------------- V slice transpose: QKV cols [3072..4096) -> Vt[B][8][32 stile][128][64] ----
__global__ __launch_bounds__(256) void vtrans_kernel(const u16* __restrict__ qkv,
                                                     u16* __restrict__ outp) {
  __shared__ unsigned tile[32][33];
  int bh = blockIdx.z;  // b*8+hv
  int t0 = blockIdx.x * 32, dv0 = blockIdx.y * 32;
  int tx = threadIdx.x & 31, ty = threadIdx.x >> 5;
  int bt_base = (bh >> 3) * T_SEQ;
  int col = 3072 + (bh & 7) * 128 + dv0 + tx;
  #pragma unroll
  for (int k2 = 0; k2 < 4; k2++)
    tile[ty * 4 + k2][tx] = qkv[(size_t)(bt_base + t0 + ty * 4 + k2) * 4096 + col];
  __syncthreads();
  const int stile = t0 >> 6, sin = (t0 & 63) + tx;
  #pragma unroll
  for (int k2 = 0; k2 < 4; k2++) {
    int dv = dv0 + ty * 4 + k2;
    outp[(((size_t)bh * 32 + stile) * 128 + dv) * 64 + sin] = (u16)tile[tx][ty * 4 + k2];
  }
}

// ---------------- flash diff-attention, S^T formulation, pipelined staging ----------------
// Qb [B][32][T][64] (rotary, *HD^-.5*log2e), Kb [B][16][T][64], Vt [B][8][32][128][64]
// S^T = K·Q^T (lane: q=l15, s=quad*4+rr); O^T = V^T·P^T. One raw barrier per step;
// tile st+1 staged (glds) during compute of tile st; per-wave vmcnt(0) + barrier = ready.
__global__ __launch_bounds__(256) void attn_kernel(const u16* __restrict__ Qb,
                                                   const u16* __restrict__ Kb,
                                                   const u16* __restrict__ Vt,
                                                   const float* __restrict__ lamp,
                                                   const float* __restrict__ g,
                                                   u16* __restrict__ attn_out) {
  __shared__ alignas(16) u16 Ks[2][64 * 64];   // XOR-swizzled, double-buffered
  __shared__ alignas(16) u16 Vs[2][128 * 64];  // XOR-swizzled, double-buffered
  __shared__ alignas(16) u16 Ps[4][16][136];   // per wave: [q][s 0..63 e0 | 64..127 e1]
  const int pr = blockIdx.x;  // handles q-tiles pr and 31-pr (33 steps total)
  const int bh = blockIdx.y;
  const int b = bh >> 4, h = bh & 15;
  const int tid = threadIdx.x, w = tid >> 6, lane = tid & 63;
  const int l15 = lane & 15, quad = lane >> 4;
  const int lr = lane >> 3, slot = lane & 7, csw = slot ^ lr;
  const float lam = lamp[0];

  // wave-uniform LDS staging bases (u16 index within tile buffer)
  u16* kd[2] = {&Ks[0][w * 1024], &Ks[1][w * 1024]};
  u16* vd[2] = {&Vs[0][w * 2048], &Vs[1][w * 2048]};
  // per-lane global source bases (tile 0)
  const u16* KgBase =
      Kb + (size_t)(b * 16 + h) * (T_SEQ * 64) + (w * 16 + lr) * 64 + csw * 8;
  const u16* VgBase =
      Vt + (size_t)(b * 8 + (h >> 1)) * (T_SEQ * 128) + w * 2048 + lr * 64 + csw * 8;

  #pragma unroll 1
  for (int half = 0; half < 2; half++) {
    const int tt = half ? 31 - pr : pr;
    const int qb = tt * 64 + w * 16;  // wave's first q row
    const int qglob = qb + l15;       // this lane's q row

    bf16x8 qf[2][2];
    #pragma unroll
    for (int e = 0; e < 2; e++)
      #pragma unroll
      for (int kk = 0; kk < 2; kk++)
        qf[e][kk] = *(const bf16x8*)&Qb[((size_t)(b * 32 + 2 * h + e) * T_SEQ + qb + l15) * 64 +
                                        kk * 32 + quad * 8];

    const u16* Kp = KgBase;  // next tile to stage; advances by 4096 u16 (8 KB)
    const u16* Vp = VgBase;  // advances by 8192 u16 (16 KB)
    // stage tile 0 into buffer 0
    glds16(Kp, kd[0]); glds16(Kp + 512, kd[0] + 512);
    glds16(Vp, vd[0]); glds16(Vp + 512, vd[0] + 512);
    glds16(Vp + 1024, vd[0] + 1024); glds16(Vp + 1536, vd[0] + 1536);
    Kp += 4096; Vp += 8192;

    f32x4 o[2][8];
    float lsum[2] = {0.f, 0.f};
    #pragma unroll
    for (int e = 0; e < 2; e++)
      #pragma unroll
      for (int nt = 0; nt < 8; nt++) o[e][nt] = (f32x4){0.f, 0.f, 0.f, 0.f};

    int st = 0;
    auto step = [&](const u16* KC, const u16* VC, u16* KDN, u16* VDN) {
      // my stage(st) landed in LDS; barrier => everyone's landed AND everyone
      // finished reading the buffer stage(st+1) will overwrite.
      asm volatile("s_waitcnt vmcnt(0)" ::: "memory");
      asm volatile("s_barrier" ::: "memory");
      if (st < tt) {  // prefetch tile st+1 into the other buffer (hidden by compute)
        glds16(Kp, KDN); glds16(Kp + 512, KDN + 512);
        glds16(Vp, VDN); glds16(Vp + 512, VDN + 512);
        glds16(Vp + 1024, VDN + 1024); glds16(Vp + 1536, VDN + 1536);
        Kp += 4096; Vp += 8192;
      }
      const int s0 = st * 64;
      bf16x8 kf[4][2];
      #pragma unroll
      for (int j = 0; j < 4; j++) {
        const int rk = j * 16 + l15;
        #pragma unroll
        for (int kk = 0; kk < 2; kk++)
          kf[j][kk] = *(const bf16x8*)&KC[rk * 64 + (((kk * 4 + quad) ^ (rk & 7)) << 3)];
      }
      #pragma unroll
      for (int e = 0; e < 2; e++) {
        f32x4 sc[4];
        #pragma unroll
        for (int j = 0; j < 4; j++) {  // S^T: lane holds s=quad*4+rr, q=l15
          f32x4 z = {0.f, 0.f, 0.f, 0.f};
          z = mfma16(kf[j][0], qf[e][0], z);
          sc[j] = mfma16(kf[j][1], qf[e][1], z);
        }
        if (st == tt) {  // causal mask (diagonal tile only)
          #pragma unroll
          for (int j = 0; j < 4; j++) {
            int srow = s0 + j * 16 + quad * 4;
            #pragma unroll
            for (int rr = 0; rr < 4; rr++)
              if (srow + rr > qglob) sc[j][rr] = -1e30f;
          }
        }
        float ls = 0.f;
        #pragma unroll
        for (int j = 0; j < 4; j++) {
          #pragma unroll
          for (int rr = 0; rr < 4; rr++) {
            float p = exp2r(sc[j][rr]);  // log2e folded into Q scale
            sc[j][rr] = p;
            ls += p;
          }
          uint2 pk;
          pk.x = pkhi(sc[j][0], sc[j][1]);
          pk.y = pkhi(sc[j][2], sc[j][3]);
          *(uint2*)&Ps[w][l15][e * 64 + j * 16 + quad * 4] = pk;
        }
        lsum[e] += ls;
      }
      asm volatile("s_waitcnt lgkmcnt(0)" ::: "memory");
      bf16x8 pa[2][2];
      #pragma unroll
      for (int e = 0; e < 2; e++)
        #pragma unroll
        for (int kk = 0; kk < 2; kk++)
          pa[e][kk] = *(const bf16x8*)&Ps[w][l15][e * 64 + kk * 32 + quad * 8];
      asm volatile("" ::: "memory");
      #pragma unroll
      for (int nt = 0; nt < 8; nt++) {  // O^T = V^T·P^T
        const int rv = nt * 16 + l15;
        bf16x8 vf0 = *(const bf16x8*)&VC[rv * 64 + ((quad ^ (rv & 7)) << 3)];
        bf16x8 vf1 = *(const bf16x8*)&VC[rv * 64 + (((4 + quad) ^ (rv & 7)) << 3)];
        o[0][nt] = mfma16(vf0, pa[0][0], o[0][nt]);
        o[0][nt] = mfma16(vf1, pa[0][1], o[0][nt]);
        o[1][nt] = mfma16(vf0, pa[1][0], o[1][nt]);
        o[1][nt] = mfma16(vf1, pa[1][1], o[1][nt]);
      }
    };
    while (true) {
      step(Ks[0], Vs[0], kd[1], vd[1]);
      if (++st > tt) break;
      step(Ks[1], Vs[1], kd[0], vd[0]);
      if (++st > tt) break;
    }
    // all waves done reading K/V buffers before next half re-stages them
    asm volatile("s_barrier" ::: "memory");

    // lane holds O^T[d = nt*16+quad*4+rr][q = l15]; reduce sums over quads (s-dim)
    float l0 = lsum[0], l1 = lsum[1];
    l0 += __shfl_xor(l0, 16); l0 += __shfl_xor(l0, 32);
    l1 += __shfl_xor(l1, 16); l1 += __shfl_xor(l1, 32);
    const float il0 = 1.f / l0, il1 = lam / l1;
    float ssq = 0.f;
    #pragma unroll
    for (int nt = 0; nt < 8; nt++)
      #pragma unroll
      for (int rr = 0; rr < 4; rr++) {
        float v = o[0][nt][rr] * il0 - o[1][nt][rr] * il1;
        o[0][nt][rr] = v;
        ssq += v * v;
      }
    ssq += __shfl_xor(ssq, 16);
    ssq += __shfl_xor(ssq, 32);
    const float rsc = rsqrtf(ssq * (1.f / 128.f) + 1e-6f) * 0.2163942334683756f;
    // stage normalized rows to LDS (transpose back): Ps[q=l15][d = 0..127]
    #pragma unroll
    for (int nt = 0; nt < 8; nt++) {
      float4 gv = *(const float4*)&g[nt * 16 + quad * 4];
      uint2 pk;
      pk.x = (unsigned)f2b(o[0][nt][0] * rsc * gv.x) |
             ((unsigned)f2b(o[0][nt][1] * rsc * gv.y) << 16);
      pk.y = (unsigned)f2b(o[0][nt][2] * rsc * gv.z) |
             ((unsigned)f2b(o[0][nt][3] * rsc * gv.w) << 16);
      *(uint2*)&Ps[w][l15][nt * 16 + quad * 4] = pk;
    }
    asm volatile("s_waitcnt lgkmcnt(0)" ::: "memory");
    // full-coverage read-back: 4 iters x 64 lanes x 8 u16 = 2048 = 16 rows x 128 cols
    #pragma unroll
    for (int i = 0; i < 4; i++) {
      const int r = (lane >> 4) + i * 4, c = (lane & 15) * 8;
      bf16x8 ov = *(const bf16x8*)&Ps[w][r][c];
      *(bf16x8*)&attn_out[(size_t)(b * T_SEQ + qb + r) * 2048 + h * 128 + c] = ov;
    }
  }
}

extern "C" void kernel_launch(void* const* d_in, const int* in_sizes, int n_in, void* d_out,
                              int out_size, void* d_ws, size_t ws_size, hipStream_t stream) {
  const float* x = (const float*)d_in[0];
  const float* Wq = (const float*)d_in[1];
  const float* Wk = (const float*)d_in[2];
  const float* Wv = (const float*)d_in[3];
  const float* Wo = (const float*)d_in[4];
  const float* lq1 = (const float*)d_in[5];
  const float* lk1 = (const float*)d_in[6];
  const float* lq2 = (const float*)d_in[7];
  const float* lk2 = (const float*)d_in[8];
  const float* g = (const float*)d_in[9];

  char* ws = (char*)d_ws;
  u16* WT = (u16*)(ws);                 // [4096][2048] = [WqT;WkT;WvT], 16 MB
  u16* WoT = (u16*)(ws + 16777216);     // [2048][2048], 8 MB
  u16* xbf = (u16*)(ws + 25165824);     // [4096][2048], 16 MB
  u16* QKV = (u16*)(ws + 41943040);     // [4096][4096], 32 MB
  u16* Qb = (u16*)(ws + 75497472);      // [2][32][2048][64], 16 MB
  u16* Kb = (u16*)(ws + 92274688);      // [2][16][2048][64], 8 MB
  u16* Vt = (u16*)(ws + 100663296);     // [2][8][32][128][64], 8 MB
  u16* Attn = (u16*)(ws + 109051904);   // [4096][2048], 16 MB
  float* lam = (float*)(ws + 125829120);

  lam_kernel<<<1, 64, 0, stream>>>(lq1, lk1, lq2, lk2, lam);
  convert_kernel<<<8192, 256, 0, stream>>>(x, xbf, 8388608);
  transpose_kernel<<<dim3(64, 64), 256, 0, stream>>>(Wq, WT, 2048, 2048);
  transpose_kernel<<<dim3(32, 64), 256, 0, stream>>>(Wk, WT + (size_t)2048 * 2048, 2048, 1024);
  transpose_kernel<<<dim3(32, 64), 256, 0, stream>>>(Wv, WT + (size_t)3072 * 2048, 2048, 1024);
  transpose_kernel<<<dim3(64, 64), 256, 0, stream>>>(Wo, WoT, 2048, 2048);
  gemm128_kernel<true><<<dim3(32, 32), 256, 0, stream>>>(xbf, WT, QKV, 4096, 2048);
  // Q scale = HD^-0.5 * log2(e) so scores feed exp2 directly
  rotary_kernel<<<16384, 256, 0, stream>>>(QKV, Qb, 5, 0, 0.18033688011112042f);
  rotary_kernel<<<8192, 256, 0, stream>>>(QKV, Kb, 4, 2048, 1.0f);
  vtrans_kernel<<<dim3(64, 4, 16), 256, 0, stream>>>(QKV, Vt);
  attn_kernel<<<dim3(16, 32), 256, 0, stream>>>(Qb, Kb, Vt, lam, g, Attn);
  gemm128_kernel<false><<<dim3(16, 32), 256, 0, stream>>>(Attn, WoT, d_out, 2048, 2048);
}

// Round 7
// 368.707 us; speedup vs baseline: 1.0752x; 1.0752x over previous
//
#include <hip/hip_runtime.h>

#define T_SEQ 2048

typedef __bf16 bf16x8 __attribute__((ext_vector_type(8)));
typedef float f32x4 __attribute__((ext_vector_type(4)));
typedef unsigned short u16;

__device__ __forceinline__ u16 f2b(float f) {
  unsigned u = __float_as_uint(f);
  unsigned r = 0x7fffu + ((u >> 16) & 1u);
  return (u16)((u + r) >> 16);
}
__device__ __forceinline__ float b2f(u16 v) {
  return __uint_as_float(((unsigned)v) << 16);
}
__device__ __forceinline__ f32x4 mfma16(bf16x8 a, bf16x8 b, f32x4 c) {
  return __builtin_amdgcn_mfma_f32_16x16x32_bf16(a, b, c, 0, 0, 0);
}
// pack two f32 -> two bf16 (RTZ) in ONE v_perm_b32 (truncation ~ bf16 noise).
__device__ __forceinline__ unsigned pkhi(float lo, float hi) {
  return __builtin_amdgcn_perm(__float_as_uint(hi), __float_as_uint(lo), 0x07060302u);
}
// raw exp2 (no OCML denormal fixup; -1e30 underflows to 0 which is what we want)
#if defined(__has_builtin)
#if __has_builtin(__builtin_amdgcn_exp2f)
#define HAVE_RAW_EXP2 1
#endif
#endif
__device__ __forceinline__ float exp2r(float x) {
#ifdef HAVE_RAW_EXP2
  return __builtin_amdgcn_exp2f(x);
#else
  float r;
  asm("v_exp_f32 %0, %1" : "=v"(r) : "v"(x));
  return r;
#endif
}
// async global->LDS, 16B per lane; LDS dest = wave-uniform base + lane*16
__device__ __forceinline__ void glds16(const void* g, void* s) {
  __builtin_amdgcn_global_load_lds(
      (const __attribute__((address_space(1))) void*)(uintptr_t)g,
      (__attribute__((address_space(3))) void*)(unsigned)(uintptr_t)s, 16, 0, 0);
}

// ---------------- lambda scalar ----------------
__global__ void lam_kernel(const float* __restrict__ q1, const float* __restrict__ k1,
                           const float* __restrict__ q2, const float* __restrict__ k2,
                           float* __restrict__ outp) {
  int l = threadIdx.x;
  float a = q1[l] * k1[l];
  float c = q2[l] * k2[l];
  #pragma unroll
  for (int off = 32; off > 0; off >>= 1) {
    a += __shfl_down(a, off);
    c += __shfl_down(c, off);
  }
  if (l == 0) outp[0] = expf(a) - expf(c) + 0.7836057665316244f;  // + LAMBDA_INIT
}

// ---------------- fp32 -> bf16 convert ----------------
__global__ __launch_bounds__(256) void convert_kernel(const float* __restrict__ in,
                                                      u16* __restrict__ outp, int n) {
  int i = (blockIdx.x * 256 + threadIdx.x) * 4;
  if (i >= n) return;
  float4 v = *(const float4*)(in + i);
  ushort4 pk;
  pk.x = f2b(v.x); pk.y = f2b(v.y); pk.z = f2b(v.z); pk.w = f2b(v.w);
  *(ushort4*)(outp + i) = pk;
}

// ---------------- fused W transpose: Wq/Wk/Wv/Wo fp32 -> bf16 WT[6144][2048] ----------------
// rows 0..2048 = Wq^T, 2048..3072 = Wk^T, 3072..4096 = Wv^T, 4096..6144 = Wo^T
__global__ __launch_bounds__(256) void transposeW_kernel(const float* __restrict__ Wq,
                                                         const float* __restrict__ Wk,
                                                         const float* __restrict__ Wv,
                                                         const float* __restrict__ Wo,
                                                         u16* __restrict__ outp) {
  __shared__ float tile[32][33];
  const int ro0 = blockIdx.y * 32;  // out-row base (0..6144), never crosses a segment
  const int r0 = blockIdx.x * 32;   // source-row base (0..2048)
  const float* src; int C, cbase;
  if (ro0 < 2048)      { src = Wq; C = 2048; cbase = 0; }
  else if (ro0 < 3072) { src = Wk; C = 1024; cbase = 2048; }
  else if (ro0 < 4096) { src = Wv; C = 1024; cbase = 3072; }
  else                 { src = Wo; C = 2048; cbase = 4096; }
  const int cs0 = ro0 - cbase;
  const int tx = threadIdx.x & 31, ty = threadIdx.x >> 5;
  #pragma unroll
  for (int k2 = 0; k2 < 4; k2++)
    tile[ty * 4 + k2][tx] = src[(size_t)(r0 + ty * 4 + k2) * C + cs0 + tx];
  __syncthreads();
  #pragma unroll
  for (int k2 = 0; k2 < 4; k2++)
    outp[(size_t)(ro0 + ty * 4 + k2) * 2048 + r0 + tx] = f2b(tile[tx][ty * 4 + k2]);
}

// ---------------- m97-style GEMM: C[M][N] = A[M][K] @ BT[N][K]^T ----------------
template <bool OUT_BF16>
__global__ __launch_bounds__(256) void gemm128_kernel(const u16* __restrict__ A,
                                                      const u16* __restrict__ BT,
                                                      void* __restrict__ C, int N, int K) {
  __shared__ alignas(16) u16 As[128 * 64];
  __shared__ alignas(16) u16 Bs[128 * 64];
  const int tid = threadIdx.x, w = tid >> 6, lane = tid & 63;
  const int l15 = lane & 15, quad = lane >> 4;
  const int m0 = blockIdx.y * 128, n0 = blockIdx.x * 128;
  const int wm = (w >> 1) * 64, wn = (w & 1) * 64;
  const int lr = lane >> 3, slot = lane & 7, csw = slot ^ lr;
  f32x4 acc[4][4];
  #pragma unroll
  for (int mt = 0; mt < 4; mt++)
    #pragma unroll
    for (int nt = 0; nt < 4; nt++) acc[mt][nt] = (f32x4){0.f, 0.f, 0.f, 0.f};
  const u16* Ag = A + (size_t)(m0 + w * 32 + lr) * K + csw * 8;
  const u16* Bg = BT + (size_t)(n0 + w * 32 + lr) * K + csw * 8;
  u16* Asd = As + (w * 32) * 64;
  u16* Bsd = Bs + (w * 32) * 64;
  for (int kt = 0; kt < K; kt += 64) {
    #pragma unroll
    for (int i = 0; i < 4; i++) {
      glds16(Ag + kt + (size_t)(i * 8) * K, Asd + i * 512);
      glds16(Bg + kt + (size_t)(i * 8) * K, Bsd + i * 512);
    }
    __syncthreads();
    #pragma unroll
    for (int kk = 0; kk < 2; kk++) {
      bf16x8 am[4], bn[4];
      #pragma unroll
      for (int t = 0; t < 4; t++) {
        const int ra = wm + t * 16 + l15;
        am[t] = *(const bf16x8*)&As[ra * 64 + (((kk * 4 + quad) ^ (ra & 7)) << 3)];
        const int rb = wn + t * 16 + l15;
        bn[t] = *(const bf16x8*)&Bs[rb * 64 + (((kk * 4 + quad) ^ (rb & 7)) << 3)];
      }
      #pragma unroll
      for (int mt = 0; mt < 4; mt++)
        #pragma unroll
        for (int nt = 0; nt < 4; nt++) acc[mt][nt] = mfma16(am[mt], bn[nt], acc[mt][nt]);
    }
    __syncthreads();
  }
  const int row = m0 + wm + quad * 4;
  #pragma unroll
  for (int mt = 0; mt < 4; mt++) {
    #pragma unroll
    for (int nt = 0; nt < 4; nt++) {
      const int col = n0 + wn + nt * 16 + l15;
      #pragma unroll
      for (int rr = 0; rr < 4; rr++) {
        if (OUT_BF16)
          ((u16*)C)[(size_t)(row + mt * 16 + rr) * N + col] = f2b(acc[mt][nt][rr]);
        else
          ((float*)C)[(size_t)(row + mt * 16 + rr) * N + col] = acc[mt][nt][rr];
      }
    }
  }
}

// ---------------- merged rotary: QKV -> Qb (heads 0..31, *qscale) and Kb (heads 32..47) ------
__global__ __launch_bounds__(256) void rotary_kernel(const u16* __restrict__ qkv,
                                                     u16* __restrict__ Qb,
                                                     u16* __restrict__ Kb, float qscale) {
  int idx = blockIdx.x * 256 + threadIdx.x;
  int i = idx & 31;
  int bt = (idx >> 5) & 4095;
  int hh = idx >> 17;  // 0..47 (wave-uniform)
  int t = bt & (T_SEQ - 1), b = bt >> 11;
  bool isq = hh < 32;
  int col = isq ? hh * 64 : 2048 + (hh - 32) * 64;
  size_t inb = (size_t)bt * 4096 + col + i;
  float x1 = b2f(qkv[inb]);
  float x2 = b2f(qkv[inb + 32]);
  float invf = exp2f(-(float)i * 0.4152410118609203f);
  float ang = (float)t * invf;
  float c = cosf(ang), s = sinf(ang);
  float scale = isq ? qscale : 1.0f;
  float o1 = (x1 * c + x2 * s) * scale;
  float o2 = (x2 * c - x1 * s) * scale;
  u16* outp = isq ? (Qb + (size_t)(b * 32 + hh) * (T_SEQ * 64))
                  : (Kb + (size_t)(b * 16 + hh - 32) * (T_SEQ * 64));
  size_t ob = (size_t)t * 64 + i;
  outp[ob] = f2b(o1);
  outp[ob + 32] = f2b(o2);
}

// ---------------- V slice transpose: QKV cols [3072..4096) -> Vt[B][8][32 stile][128][64] ----
__global__ __launch_bounds__(256) void vtrans_kernel(const u16* __restrict__ qkv,
                                                     u16* __restrict__ outp) {
  __shared__ unsigned tile[32][33];
  int bh = blockIdx.z;  // b*8+hv
  int t0 = blockIdx.x * 32, dv0 = blockIdx.y * 32;
  int tx = threadIdx.x & 31, ty = threadIdx.x >> 5;
  int bt_base = (bh >> 3) * T_SEQ;
  int col = 3072 + (bh & 7) * 128 + dv0 + tx;
  #pragma unroll
  for (int k2 = 0; k2 < 4; k2++)
    tile[ty * 4 + k2][tx] = qkv[(size_t)(bt_base + t0 + ty * 4 + k2) * 4096 + col];
  __syncthreads();
  const int stile = t0 >> 6, sin = (t0 & 63) + tx;
  #pragma unroll
  for (int k2 = 0; k2 < 4; k2++) {
    int dv = dv0 + ty * 4 + k2;
    outp[(((size_t)bh * 32 + stile) * 128 + dv) * 64 + sin] = (u16)tile[tx][ty * 4 + k2];
  }
}

// ---------------- flash diff-attention, S^T formulation ----------------
// Qb [B][32][T][64] (rotary, *HD^-.5*log2e), Kb [B][16][T][64], Vt [B][8][32][128][64]
// S^T = K·Q^T (lane: q=l15, s=quad*4+rr); O^T = V^T·P^T.
__global__ __launch_bounds__(256) void attn_kernel(const u16* __restrict__ Qb,
                                                   const u16* __restrict__ Kb,
                                                   const u16* __restrict__ Vt,
                                                   const float* __restrict__ lamp,
                                                   const float* __restrict__ g,
                                                   u16* __restrict__ attn_out) {
  __shared__ alignas(16) u16 Ks[64 * 64];    // XOR-swizzled
  __shared__ alignas(16) u16 Vs[128 * 64];   // XOR-swizzled
  __shared__ alignas(16) u16 Ps[4][16][136]; // per wave: [q][s 0..63 e0 | 64..127 e1]
  const int pr = blockIdx.x;  // handles q-tiles pr and 31-pr (33 steps total)
  const int bh = blockIdx.y;
  const int b = bh >> 4, h = bh & 15;
  const int tid = threadIdx.x, w = tid >> 6, lane = tid & 63;
  const int l15 = lane & 15, quad = lane >> 4;
  const int lr = lane >> 3, slot = lane & 7, csw = slot ^ lr;
  const float lam = lamp[0];

  // per-lane global staging bases (tile-contiguous: K tile = 4096 u16, V tile = 8192 u16)
  const u16* Kg = Kb + (size_t)(b * 16 + h) * (T_SEQ * 64) + (w * 16 + lr) * 64 + csw * 8;
  const u16* Vg = Vt + (size_t)(b * 8 + (h >> 1)) * (T_SEQ * 128) + w * 2048 + lr * 64 + csw * 8;
  u16* kd = &Ks[w * 1024];
  u16* vd = &Vs[w * 2048];

  #pragma unroll 1
  for (int half = 0; half < 2; half++) {
    const int tt = half ? 31 - pr : pr;
    const int qb = tt * 64 + w * 16;  // wave's first q row
    const int qglob = qb + l15;       // this lane's q row

    bf16x8 qf[2][2];
    #pragma unroll
    for (int e = 0; e < 2; e++)
      #pragma unroll
      for (int kk = 0; kk < 2; kk++)
        qf[e][kk] = *(const bf16x8*)&Qb[((size_t)(b * 32 + 2 * h + e) * T_SEQ + qb + l15) * 64 +
                                        kk * 32 + quad * 8];

    f32x4 o[2][8];
    float lsum[2] = {0.f, 0.f};
    #pragma unroll
    for (int e = 0; e < 2; e++)
      #pragma unroll
      for (int nt = 0; nt < 8; nt++) o[e][nt] = (f32x4){0.f, 0.f, 0.f, 0.f};

    for (int st = 0; st <= tt; st++) {
      const u16* kp = Kg + st * 4096;
      const u16* vp = Vg + st * 8192;
      glds16(kp, kd); glds16(kp + 512, kd + 512);
      glds16(vp, vd); glds16(vp + 512, vd + 512);
      glds16(vp + 1024, vd + 1024); glds16(vp + 1536, vd + 1536);
      __syncthreads();

      bf16x8 kf[4][2];
      #pragma unroll
      for (int j = 0; j < 4; j++) {
        const int rk = j * 16 + l15;
        #pragma unroll
        for (int kk = 0; kk < 2; kk++)
          kf[j][kk] = *(const bf16x8*)&Ks[rk * 64 + (((kk * 4 + quad) ^ (rk & 7)) << 3)];
      }

      #pragma unroll
      for (int e = 0; e < 2; e++) {
        f32x4 sc[4];
        #pragma unroll
        for (int j = 0; j < 4; j++) {  // S^T: lane holds s=quad*4+rr, q=l15
          f32x4 z = {0.f, 0.f, 0.f, 0.f};
          z = mfma16(kf[j][0], qf[e][0], z);
          sc[j] = mfma16(kf[j][1], qf[e][1], z);
        }
        if (st == tt) {  // causal mask (diagonal tile only)
          #pragma unroll
          for (int j = 0; j < 4; j++) {
            int srow = st * 64 + j * 16 + quad * 4;
            #pragma unroll
            for (int rr = 0; rr < 4; rr++)
              if (srow + rr > qglob) sc[j][rr] = -1e30f;
          }
        }
        float ls = 0.f;
        #pragma unroll
        for (int j = 0; j < 4; j++) {
          #pragma unroll
          for (int rr = 0; rr < 4; rr++) {
            float p = exp2r(sc[j][rr]);  // log2e folded into Q scale
            sc[j][rr] = p;
            ls += p;
          }
          uint2 pk;
          pk.x = pkhi(sc[j][0], sc[j][1]);
          pk.y = pkhi(sc[j][2], sc[j][3]);
          *(uint2*)&Ps[w][l15][e * 64 + j * 16 + quad * 4] = pk;
        }
        lsum[e] += ls;
      }
      asm volatile("s_waitcnt lgkmcnt(0)" ::: "memory");
      bf16x8 pa[2][2];
      #pragma unroll
      for (int e = 0; e < 2; e++)
        #pragma unroll
        for (int kk = 0; kk < 2; kk++)
          pa[e][kk] = *(const bf16x8*)&Ps[w][l15][e * 64 + kk * 32 + quad * 8];
      asm volatile("" ::: "memory");
      #pragma unroll
      for (int nt = 0; nt < 8; nt++) {  // O^T = V^T·P^T
        const int rv = nt * 16 + l15;
        bf16x8 vf0 = *(const bf16x8*)&Vs[rv * 64 + ((quad ^ (rv & 7)) << 3)];
        bf16x8 vf1 = *(const bf16x8*)&Vs[rv * 64 + (((4 + quad) ^ (rv & 7)) << 3)];
        o[0][nt] = mfma16(vf0, pa[0][0], o[0][nt]);
        o[0][nt] = mfma16(vf1, pa[0][1], o[0][nt]);
        o[1][nt] = mfma16(vf0, pa[1][0], o[1][nt]);
        o[1][nt] = mfma16(vf1, pa[1][1], o[1][nt]);
      }
      __syncthreads();
    }

    // lane holds O^T[d = nt*16+quad*4+rr][q = l15]; reduce sums over quads (s-dim)
    float l0 = lsum[0], l1 = lsum[1];
    l0 += __shfl_xor(l0, 16); l0 += __shfl_xor(l0, 32);
    l1 += __shfl_xor(l1, 16); l1 += __shfl_xor(l1, 32);
    const float il0 = 1.f / l0, il1 = lam / l1;
    float ssq = 0.f;
    #pragma unroll
    for (int nt = 0; nt < 8; nt++)
      #pragma unroll
      for (int rr = 0; rr < 4; rr++) {
        float v = o[0][nt][rr] * il0 - o[1][nt][rr] * il1;
        o[0][nt][rr] = v;
        ssq += v * v;
      }
    ssq += __shfl_xor(ssq, 16);
    ssq += __shfl_xor(ssq, 32);
    const float rsc = rsqrtf(ssq * (1.f / 128.f) + 1e-6f) * 0.2163942334683756f;
    // stage normalized rows to LDS (transpose back): Ps[q=l15][d = 0..127]
    #pragma unroll
    for (int nt = 0; nt < 8; nt++) {
      float4 gv = *(const float4*)&g[nt * 16 + quad * 4];
      uint2 pk;
      pk.x = (unsigned)f2b(o[0][nt][0] * rsc * gv.x) |
             ((unsigned)f2b(o[0][nt][1] * rsc * gv.y) << 16);
      pk.y = (unsigned)f2b(o[0][nt][2] * rsc * gv.z) |
             ((unsigned)f2b(o[0][nt][3] * rsc * gv.w) << 16);
      *(uint2*)&Ps[w][l15][nt * 16 + quad * 4] = pk;
    }
    asm volatile("s_waitcnt lgkmcnt(0)" ::: "memory");
    // full-coverage read-back: 4 iters x 64 lanes x 8 u16 = 2048 = 16 rows x 128 cols
    #pragma unroll
    for (int i = 0; i < 4; i++) {
      const int r = (lane >> 4) + i * 4, c = (lane & 15) * 8;
      bf16x8 ov = *(const bf16x8*)&Ps[w][r][c];
      *(bf16x8*)&attn_out[(size_t)(b * T_SEQ + qb + r) * 2048 + h * 128 + c] = ov;
    }
    __syncthreads();  // protect Ks/Vs/Ps before next half
  }
}

extern "C" void kernel_launch(void* const* d_in, const int* in_sizes, int n_in, void* d_out,
                              int out_size, void* d_ws, size_t ws_size, hipStream_t stream) {
  const float* x = (const float*)d_in[0];
  const float* Wq = (const float*)d_in[1];
  const float* Wk = (const float*)d_in[2];
  const float* Wv = (const float*)d_in[3];
  const float* Wo = (const float*)d_in[4];
  const float* lq1 = (const float*)d_in[5];
  const float* lk1 = (const float*)d_in[6];
  const float* lq2 = (const float*)d_in[7];
  const float* lk2 = (const float*)d_in[8];
  const float* g = (const float*)d_in[9];

  char* ws = (char*)d_ws;
  u16* WT = (u16*)(ws);                 // [6144][2048]: WqT;WkT;WvT;WoT, 24 MB
  u16* xbf = (u16*)(ws + 25165824);     // [4096][2048], 16 MB
  u16* QKV = (u16*)(ws + 41943040);     // [4096][4096], 32 MB
  u16* Qb = (u16*)(ws + 75497472);      // [2][32][2048][64], 16 MB
  u16* Kb = (u16*)(ws + 92274688);      // [2][16][2048][64], 8 MB
  u16* Vt = (u16*)(ws + 100663296);     // [2][8][32][128][64], 8 MB
  u16* Attn = (u16*)(ws + 109051904);   // [4096][2048], 16 MB
  float* lam = (float*)(ws + 125829120);

  lam_kernel<<<1, 64, 0, stream>>>(lq1, lk1, lq2, lk2, lam);
  convert_kernel<<<8192, 256, 0, stream>>>(x, xbf, 8388608);
  transposeW_kernel<<<dim3(64, 192), 256, 0, stream>>>(Wq, Wk, Wv, Wo, WT);
  gemm128_kernel<true><<<dim3(32, 32), 256, 0, stream>>>(xbf, WT, QKV, 4096, 2048);
  // Q scale = HD^-0.5 * log2(e) so scores feed exp2 directly
  rotary_kernel<<<24576, 256, 0, stream>>>(QKV, Qb, Kb, 0.18033688011112042f);
  vtrans_kernel<<<dim3(64, 4, 16), 256, 0, stream>>>(QKV, Vt);
  attn_kernel<<<dim3(16, 32), 256, 0, stream>>>(Qb, Kb, Vt, lam, g, Attn);
  gemm128_kernel<false><<<dim3(16, 32), 256, 0, stream>>>(Attn, WT + (size_t)4096 * 2048, d_out,
                                                          2048, 2048);
}